// Round 3
// baseline (263.784 us; speedup 1.0000x reference)
//
#include <hip/hip_runtime.h>

#define H_ 56
#define W_ 56
#define HW_ 3136
#define CIN_ 256
#define COUT_ 256

typedef __attribute__((ext_vector_type(8))) short short8;
typedef __attribute__((ext_vector_type(4))) float f32x4;

// Pre-swizzled bf16 weights, written by prep_weights each launch (idempotent).
// Layout: [bm][kt][e], e = m*32 + col, content = bf16(W[bm*128+m][kt*32 + (col ^ swz32(m))])
__device__ unsigned short g_wbf[COUT_ * CIN_];

__device__ __forceinline__ int swz32(int n) { return ((n ^ (n >> 3)) & 3) << 3; }

__device__ __forceinline__ unsigned short f2bf(float f) {
  union { float f; unsigned int i; } v; v.f = f;
  unsigned int b = v.i + (0x7fffu + ((v.i >> 16) & 1u));  // RNE
  return (unsigned short)(b >> 16);
}

__device__ __forceinline__ void gload_lds16(const unsigned short* g, unsigned short* l) {
  __builtin_amdgcn_global_load_lds(
      (const __attribute__((address_space(1))) unsigned int*)g,
      (__attribute__((address_space(3))) unsigned int*)l, 16, 0, 0);
}

__device__ __forceinline__ void shift_decode(int c, int& dx, int& dy) {
  if (c < 102)      { dy = 0; dx = (c < 51) ? 0 : 1; }
  else if (c < 153) { dx = -1; dy = 0; }
  else if (c < 204) { dx = 0;  dy = 1; }
  else              { dx = 0;  dy = -1; }
}

__global__ __launch_bounds__(256)
void prep_weights(const float* __restrict__ wgt) {
  int idx  = blockIdx.x * 256 + threadIdx.x;   // 0..65535
  int tile = idx >> 12;                        // bm*8 + kt
  int bm = tile >> 3, kt = tile & 7;
  int e   = idx & 4095;
  int m   = e >> 5, col = e & 31;
  int o   = bm * 128 + m;
  int k   = kt * 32 + (col ^ swz32(m));
  g_wbf[idx] = f2bf(wgt[o * CIN_ + k]);
}

// Load next x slice into registers (shift applied later at LDS-write time).
__device__ __forceinline__ void load_x(const float* __restrict__ x, size_t xb,
                                       int hh, int w0, int c,
                                       float4& p0, float4& p1, float& pe) {
  int dx, dy; shift_decode(c, dx, dy);
  int h2 = hh - dy;
  p0 = make_float4(0.f, 0.f, 0.f, 0.f);
  p1 = make_float4(0.f, 0.f, 0.f, 0.f);
  pe = 0.f;
  if ((unsigned)h2 < (unsigned)H_) {
    const float* row = x + xb + (size_t)c * HW_ + h2 * W_;
    p0 = *(const float4*)(row + w0);
    p1 = *(const float4*)(row + w0 + 4);
    if (dx == 1)       { if (w0 > 0)      pe = row[w0 - 1]; }
    else if (dx == -1) { if (w0 + 8 < W_) pe = row[w0 + 8]; }
  }
}

// Apply the W-shift in registers and scatter bf16 into the (transposed) B tile.
__device__ __forceinline__ void write_b(unsigned short* __restrict__ B,
                                        int nloc0, int krow, int c,
                                        const float4& p0, const float4& p1, float pe) {
  int dx, dy; shift_decode(c, dx, dy);
  float s[8] = {p0.x, p0.y, p0.z, p0.w, p1.x, p1.y, p1.z, p1.w};
  float vals[8];
  if (dx == 0) {
    #pragma unroll
    for (int i = 0; i < 8; ++i) vals[i] = s[i];
  } else if (dx == 1) {          // y[w] = x[w-1]
    #pragma unroll
    for (int i = 7; i >= 1; --i) vals[i] = s[i - 1];
    vals[0] = pe;
  } else {                       // dx == -1: y[w] = x[w+1]
    #pragma unroll
    for (int i = 0; i < 7; ++i) vals[i] = s[i + 1];
    vals[7] = pe;
  }
  #pragma unroll
  for (int i = 0; i < 8; ++i) {
    int nl = nloc0 + i;
    B[nl * 32 + (krow ^ swz32(nl))] = f2bf(vals[i]);
  }
}

__global__ __launch_bounds__(256, 6)
void shiftconv_gemm(const float* __restrict__ x,
                    const float* __restrict__ gamma,
                    const float* __restrict__ beta,
                    const float* __restrict__ rmean,
                    const float* __restrict__ rvar,
                    float* __restrict__ out)
{
  // Double-buffered: A [128 m][32 k] bf16, B [64 n][32 k] bf16, both k-contig,
  // cols XOR-swizzled by ((row^(row>>3))&3)<<3 -> b128 frag reads conflict-free.
  __shared__ unsigned short Alds[2][128 * 32];   // 2 x 8 KB
  __shared__ unsigned short Blds[2][64 * 32];    // 2 x 4 KB
  __shared__ float bnp[256];                     // interleaved (inv, add)

  const int t = threadIdx.x;
  // XCD-bijective swizzle (nwg = 3136 = 8*392): each XCD gets a contiguous
  // wgid chunk; bm-pairs (same bn, same x slice) are adjacent -> L2 hit.
  const int orig = blockIdx.x;
  const int wgid = (orig & 7) * 392 + (orig >> 3);
  const int bm   = wgid & 1;     // 2 m-tiles of 128
  const int bn   = wgid >> 1;    // 1568 n-tiles of 64

  const int lane = t & 63;
  const int wv   = t >> 6;
  const int wm   = wv >> 1;      // wave m-half (64 rows)
  const int wn   = wv & 1;       // wave n-half (32 cols)
  const int quad = lane >> 4;
  const int l15  = lane & 15;

  if (t < 128) {
    int o = bm * 128 + t;
    float inv = gamma[o] * rsqrtf(rvar[o] + 1e-5f);
    bnp[2 * t]     = inv;
    bnp[2 * t + 1] = beta[o] - rmean[o] * inv;
  }

  // ---- B staging decode (constant across K loop): 8 n x 1 k per thread ----
  const int chunk  = t & 7;           // 8 chunks of 8 n
  const int krow   = t >> 3;          // 0..31 = k within tile
  const int nloc0  = chunk * 8;
  const int nglob0 = bn * 64 + nloc0;
  const int bidx   = nglob0 / HW_;
  const int rem    = nglob0 - bidx * HW_;
  const int hh     = rem / W_;
  const int w0     = rem - hh * W_;   // multiple of 8
  const size_t xb  = (size_t)bidx * CIN_ * HW_;

  // ---- A staging source: pre-swizzled bf16 weights ----
  const unsigned short* wsrc = g_wbf + bm * (8 * 4096) + t * 8;

  f32x4 acc[4][2];
  #pragma unroll
  for (int i = 0; i < 4; ++i)
    #pragma unroll
    for (int j = 0; j < 2; ++j)
      acc[i][j] = (f32x4){0.f, 0.f, 0.f, 0.f};

  // 2-deep x prefetch: ping-pong register sets, statically indexed (full unroll).
  float4 px0[2], px1[2];
  float  pxe[2];

  // ---- prologue ----
  {
    const unsigned short* g = wsrc;
    gload_lds16(g,        &Alds[0][wv * 512]);
    gload_lds16(g + 2048, &Alds[0][wv * 512 + 2048]);
  }
  load_x(x, xb, hh, w0, krow, px0[0], px1[0], pxe[0]);
  write_b(&Blds[0][0], nloc0, krow, krow, px0[0], px1[0], pxe[0]);
  load_x(x, xb, hh, w0, 32 + krow, px0[1], px1[1], pxe[1]);   // tile 1 in flight
  __syncthreads();

  const int kb = quad * 8;

  // ---- main loop: one barrier per K-tile; A DMA + 2-deep x prefetch in flight ----
  #pragma unroll
  for (int kt = 0; kt < 8; ++kt) {
    const int buf = kt & 1;
    const int sW  = (kt + 1) & 1;   // set holding x for tile kt+1 (consumed below)
    const int sL  = kt & 1;         // set to fill with x for tile kt+2

    if (kt + 1 < 8) {
      const unsigned short* g = wsrc + (kt + 1) * 4096;
      gload_lds16(g,        &Alds[buf ^ 1][wv * 512]);
      gload_lds16(g + 2048, &Alds[buf ^ 1][wv * 512 + 2048]);
    }
    if (kt + 2 < 8)
      load_x(x, xb, hh, w0, (kt + 2) * 32 + krow, px0[sL], px1[sL], pxe[sL]);

    short8 af[4], bfr[2];
    #pragma unroll
    for (int f = 0; f < 4; ++f) {
      int ml = wm * 64 + f * 16 + l15;
      af[f] = *(const short8*)(&Alds[buf][ml * 32 + (kb ^ swz32(ml))]);
    }
    #pragma unroll
    for (int g2 = 0; g2 < 2; ++g2) {
      int nl = wn * 32 + g2 * 16 + l15;
      bfr[g2] = *(const short8*)(&Blds[buf][nl * 32 + (kb ^ swz32(nl))]);
    }
    #pragma unroll
    for (int mf = 0; mf < 4; ++mf)
      #pragma unroll
      for (int nf = 0; nf < 2; ++nf)
        acc[mf][nf] = __builtin_amdgcn_mfma_f32_16x16x32_bf16(
            af[mf], bfr[nf], acc[mf][nf], 0, 0, 0);

    if (kt + 1 < 8)
      write_b(&Blds[buf ^ 1][0], nloc0, krow, (kt + 1) * 32 + krow,
              px0[sW], px1[sW], pxe[sW]);

    __syncthreads();
  }

  // ---- epilogue: BN + ReLU + fp32 store ----
  size_t nbase[2];
  #pragma unroll
  for (int nf = 0; nf < 2; ++nf) {
    int ng  = bn * 64 + wn * 32 + nf * 16 + l15;
    int b2  = ng / HW_;
    int hw2 = ng - b2 * HW_;
    nbase[nf] = (size_t)b2 * COUT_ * HW_ + hw2;
  }
  #pragma unroll
  for (int mf = 0; mf < 4; ++mf) {
    int mloc = wm * 64 + mf * 16 + quad * 4;   // local o for reg r=0
    float inv[4], add[4];
    #pragma unroll
    for (int r = 0; r < 4; ++r) {
      inv[r] = bnp[2 * (mloc + r)];
      add[r] = bnp[2 * (mloc + r) + 1];
    }
    size_t obase = (size_t)(bm * 128 + mloc) * HW_;
    #pragma unroll
    for (int nf = 0; nf < 2; ++nf) {
      #pragma unroll
      for (int r = 0; r < 4; ++r) {
        float v = fmaf(acc[mf][nf][r], inv[r], add[r]);
        out[nbase[nf] + obase + (size_t)r * HW_] = fmaxf(v, 0.0f);
      }
    }
  }
}

extern "C" void kernel_launch(void* const* d_in, const int* in_sizes, int n_in,
                              void* d_out, int out_size, void* d_ws, size_t ws_size,
                              hipStream_t stream) {
  const float* x     = (const float*)d_in[0];
  const float* wgt   = (const float*)d_in[1];
  const float* gamma = (const float*)d_in[2];
  const float* beta  = (const float*)d_in[3];
  const float* rmean = (const float*)d_in[4];
  const float* rvar  = (const float*)d_in[5];
  float* out = (float*)d_out;

  prep_weights<<<dim3(256), dim3(256), 0, stream>>>(wgt);
  shiftconv_gemm<<<dim3(3136), dim3(256), 0, stream>>>(x, gamma, beta, rmean, rvar, out);
}

// Round 4
// 222.420 us; speedup vs baseline: 1.1860x; 1.1860x over previous
//
#include <hip/hip_runtime.h>

#define H_ 56
#define W_ 56
#define HW_ 3136
#define CIN_ 256
#define COUT_ 256

typedef __attribute__((ext_vector_type(8))) short short8;
typedef __attribute__((ext_vector_type(4))) float f32x4;

// Pre-swizzled bf16 weights, written by prep_weights each launch (idempotent).
// Layout: [bm][kt][e], e = m*32 + col, content = bf16(W[bm*128+m][kt*32 + (col ^ swz32(m))])
__device__ unsigned short g_wbf[COUT_ * CIN_];

__device__ __forceinline__ int swz32(int n) { return ((n ^ (n >> 3)) & 3) << 3; }

__device__ __forceinline__ unsigned short f2bf(float f) {
  union { float f; unsigned int i; } v; v.f = f;
  unsigned int b = v.i + (0x7fffu + ((v.i >> 16) & 1u));  // RNE
  return (unsigned short)(b >> 16);
}

__device__ __forceinline__ void gload_lds16(const unsigned short* g, unsigned short* l) {
  __builtin_amdgcn_global_load_lds(
      (const __attribute__((address_space(1))) unsigned int*)g,
      (__attribute__((address_space(3))) unsigned int*)l, 16, 0, 0);
}

__device__ __forceinline__ void shift_decode(int c, int& dx, int& dy) {
  if (c < 102)      { dy = 0; dx = (c < 51) ? 0 : 1; }
  else if (c < 153) { dx = -1; dy = 0; }
  else if (c < 204) { dx = 0;  dy = 1; }
  else              { dx = 0;  dy = -1; }
}

__global__ __launch_bounds__(256)
void prep_weights(const float* __restrict__ wgt) {
  int idx  = blockIdx.x * 256 + threadIdx.x;   // 0..65535
  int tile = idx >> 12;                        // bm*8 + kt
  int bm = tile >> 3, kt = tile & 7;
  int e   = idx & 4095;
  int m   = e >> 5, col = e & 31;
  int o   = bm * 128 + m;
  int k   = kt * 32 + (col ^ swz32(m));
  g_wbf[idx] = f2bf(wgt[o * CIN_ + k]);
}

// Load next x slice into registers (shift applied later at LDS-write time).
__device__ __forceinline__ void load_x(const float* __restrict__ x, size_t xb,
                                       int hh, int w0, int c,
                                       float4& p0, float4& p1, float& pe) {
  int dx, dy; shift_decode(c, dx, dy);
  int h2 = hh - dy;
  p0 = make_float4(0.f, 0.f, 0.f, 0.f);
  p1 = make_float4(0.f, 0.f, 0.f, 0.f);
  pe = 0.f;
  if ((unsigned)h2 < (unsigned)H_) {
    const float* row = x + xb + (size_t)c * HW_ + h2 * W_;
    p0 = *(const float4*)(row + w0);
    p1 = *(const float4*)(row + w0 + 4);
    if (dx == 1)       { if (w0 > 0)      pe = row[w0 - 1]; }
    else if (dx == -1) { if (w0 + 8 < W_) pe = row[w0 + 8]; }
  }
}

// Apply the W-shift in registers and scatter bf16 into the (transposed) B tile.
__device__ __forceinline__ void write_b(unsigned short* __restrict__ B,
                                        int nloc0, int krow, int c,
                                        const float4& p0, const float4& p1, float pe) {
  int dx, dy; shift_decode(c, dx, dy);
  float s[8] = {p0.x, p0.y, p0.z, p0.w, p1.x, p1.y, p1.z, p1.w};
  float vals[8];
  if (dx == 0) {
    #pragma unroll
    for (int i = 0; i < 8; ++i) vals[i] = s[i];
  } else if (dx == 1) {          // y[w] = x[w-1]
    #pragma unroll
    for (int i = 7; i >= 1; --i) vals[i] = s[i - 1];
    vals[0] = pe;
  } else {                       // dx == -1: y[w] = x[w+1]
    #pragma unroll
    for (int i = 0; i < 7; ++i) vals[i] = s[i + 1];
    vals[7] = pe;
  }
  #pragma unroll
  for (int i = 0; i < 8; ++i) {
    int nl = nloc0 + i;
    B[nl * 32 + (krow ^ swz32(nl))] = f2bf(vals[i]);
  }
}

__global__ __launch_bounds__(256, 6)
void shiftconv_gemm(const float* __restrict__ x,
                    const float* __restrict__ gamma,
                    const float* __restrict__ beta,
                    const float* __restrict__ rmean,
                    const float* __restrict__ rvar,
                    float* __restrict__ out)
{
  // Double-buffered: A [128 m][32 k] bf16, B [64 n][32 k] bf16, both k-contig,
  // cols XOR-swizzled by ((row^(row>>3))&3)<<3 -> b128 frag reads conflict-free.
  __shared__ unsigned short Alds[2][128 * 32];   // 2 x 8 KB
  __shared__ unsigned short Blds[2][64 * 32];    // 2 x 4 KB
  __shared__ float bnp[256];                     // interleaved (inv, add)

  const int t = threadIdx.x;
  // XCD-bijective swizzle (nwg = 3136 = 8*392): each XCD gets a contiguous
  // wgid chunk; bm-pairs (same bn, same x slice) are adjacent -> L2 hit.
  const int orig = blockIdx.x;
  const int wgid = (orig & 7) * 392 + (orig >> 3);
  const int bm   = wgid & 1;     // 2 m-tiles of 128
  const int bn   = wgid >> 1;    // 1568 n-tiles of 64

  const int lane = t & 63;
  const int wv   = t >> 6;
  const int wm   = wv >> 1;      // wave m-half (64 rows)
  const int wn   = wv & 1;       // wave n-half (32 cols)
  const int quad = lane >> 4;
  const int l15  = lane & 15;

  if (t < 128) {
    int o = bm * 128 + t;
    float inv = gamma[o] * rsqrtf(rvar[o] + 1e-5f);
    bnp[2 * t]     = inv;
    bnp[2 * t + 1] = beta[o] - rmean[o] * inv;
  }

  // ---- B staging decode (constant across K loop): 8 n x 1 k per thread ----
  const int chunk  = t & 7;           // 8 chunks of 8 n
  const int krow   = t >> 3;          // 0..31 = k within tile
  const int nloc0  = chunk * 8;
  const int nglob0 = bn * 64 + nloc0;
  const int bidx   = nglob0 / HW_;
  const int rem    = nglob0 - bidx * HW_;
  const int hh     = rem / W_;
  const int w0     = rem - hh * W_;   // multiple of 8
  const size_t xb  = (size_t)bidx * CIN_ * HW_;

  // ---- A staging source: pre-swizzled bf16 weights ----
  const unsigned short* wsrc = g_wbf + bm * (8 * 4096) + t * 8;

  f32x4 acc[4][2];
  #pragma unroll
  for (int i = 0; i < 4; ++i)
    #pragma unroll
    for (int j = 0; j < 2; ++j)
      acc[i][j] = (f32x4){0.f, 0.f, 0.f, 0.f};

  float4 p0, p1;   // raw prefetched x (shift applied at write time)
  float  pe;       // edge element for dx = +/-1

  // ---- prologue: stage tile 0 ----
  {
    const unsigned short* g = wsrc;
    gload_lds16(g,        &Alds[0][wv * 512]);
    gload_lds16(g + 2048, &Alds[0][wv * 512 + 2048]);
  }
  load_x(x, xb, hh, w0, krow, p0, p1, pe);
  write_b(&Blds[0][0], nloc0, krow, krow, p0, p1, pe);
  __syncthreads();

  const int kb = quad * 8;
  int buf = 0;

  // ---- main loop: one barrier per K-tile; next tile's loads in flight over compute ----
  for (int kt = 0; kt < 8; ++kt) {
    if (kt < 7) {
      const unsigned short* g = wsrc + (kt + 1) * 4096;
      gload_lds16(g,        &Alds[buf ^ 1][wv * 512]);
      gload_lds16(g + 2048, &Alds[buf ^ 1][wv * 512 + 2048]);
      load_x(x, xb, hh, w0, (kt + 1) * 32 + krow, p0, p1, pe);
    }

    short8 af[4], bfr[2];
    #pragma unroll
    for (int f = 0; f < 4; ++f) {
      int ml = wm * 64 + f * 16 + l15;
      af[f] = *(const short8*)(&Alds[buf][ml * 32 + (kb ^ swz32(ml))]);
    }
    #pragma unroll
    for (int g2 = 0; g2 < 2; ++g2) {
      int nl = wn * 32 + g2 * 16 + l15;
      bfr[g2] = *(const short8*)(&Blds[buf][nl * 32 + (kb ^ swz32(nl))]);
    }
    #pragma unroll
    for (int mf = 0; mf < 4; ++mf)
      #pragma unroll
      for (int nf = 0; nf < 2; ++nf)
        acc[mf][nf] = __builtin_amdgcn_mfma_f32_16x16x32_bf16(
            af[mf], bfr[nf], acc[mf][nf], 0, 0, 0);

    if (kt < 7)
      write_b(&Blds[buf ^ 1][0], nloc0, krow, (kt + 1) * 32 + krow, p0, p1, pe);

    __syncthreads();
    buf ^= 1;
  }

  // ---- epilogue: BN + ReLU + fp32 store ----
  size_t nbase[2];
  #pragma unroll
  for (int nf = 0; nf < 2; ++nf) {
    int ng  = bn * 64 + wn * 32 + nf * 16 + l15;
    int b2  = ng / HW_;
    int hw2 = ng - b2 * HW_;
    nbase[nf] = (size_t)b2 * COUT_ * HW_ + hw2;
  }
  #pragma unroll
  for (int mf = 0; mf < 4; ++mf) {
    int mloc = wm * 64 + mf * 16 + quad * 4;   // local o for reg r=0
    float inv[4], add[4];
    #pragma unroll
    for (int r = 0; r < 4; ++r) {
      inv[r] = bnp[2 * (mloc + r)];
      add[r] = bnp[2 * (mloc + r) + 1];
    }
    size_t obase = (size_t)(bm * 128 + mloc) * HW_;
    #pragma unroll
    for (int nf = 0; nf < 2; ++nf) {
      #pragma unroll
      for (int r = 0; r < 4; ++r) {
        float v = fmaf(acc[mf][nf][r], inv[r], add[r]);
        out[nbase[nf] + obase + (size_t)r * HW_] = fmaxf(v, 0.0f);
      }
    }
  }
}

extern "C" void kernel_launch(void* const* d_in, const int* in_sizes, int n_in,
                              void* d_out, int out_size, void* d_ws, size_t ws_size,
                              hipStream_t stream) {
  const float* x     = (const float*)d_in[0];
  const float* wgt   = (const float*)d_in[1];
  const float* gamma = (const float*)d_in[2];
  const float* beta  = (const float*)d_in[3];
  const float* rmean = (const float*)d_in[4];
  const float* rvar  = (const float*)d_in[5];
  float* out = (float*)d_out;

  prep_weights<<<dim3(256), dim3(256), 0, stream>>>(wgt);
  shiftconv_gemm<<<dim3(3136), dim3(256), 0, stream>>>(x, gamma, beta, rmean, rvar, out);
}

// Round 5
// 210.727 us; speedup vs baseline: 1.2518x; 1.0555x over previous
//
#include <hip/hip_runtime.h>

#define H_ 56
#define W_ 56
#define HW_ 3136
#define CIN_ 256
#define COUT_ 256

typedef __attribute__((ext_vector_type(8))) short short8;
typedef __attribute__((ext_vector_type(4))) float f32x4;

// Pre-swizzled bf16 weights, written by prep_weights each launch (idempotent).
// Layout: [bm][kt][e], e = m*32 + col, content = bf16(W[bm*128+m][kt*32 + (col ^ swz32(m))])
__device__ unsigned short g_wbf[COUT_ * CIN_];

__device__ __forceinline__ int swz32(int n) { return ((n ^ (n >> 3)) & 3) << 3; }

__device__ __forceinline__ unsigned short f2bf(float f) {
  union { float f; unsigned int i; } v; v.f = f;
  unsigned int b = v.i + (0x7fffu + ((v.i >> 16) & 1u));  // RNE
  return (unsigned short)(b >> 16);
}

__device__ __forceinline__ void gload_lds16(const unsigned short* g, unsigned short* l) {
  __builtin_amdgcn_global_load_lds(
      (const __attribute__((address_space(1))) unsigned int*)g,
      (__attribute__((address_space(3))) unsigned int*)l, 16, 0, 0);
}

__device__ __forceinline__ void shift_decode(int c, int& dx, int& dy) {
  if (c < 102)      { dy = 0; dx = (c < 51) ? 0 : 1; }
  else if (c < 153) { dx = -1; dy = 0; }
  else if (c < 204) { dx = 0;  dy = 1; }
  else              { dx = 0;  dy = -1; }
}

__global__ __launch_bounds__(256)
void prep_weights(const float* __restrict__ wgt) {
  int idx  = blockIdx.x * 256 + threadIdx.x;   // 0..65535
  int tile = idx >> 12;                        // bm*8 + kt
  int bm = tile >> 3, kt = tile & 7;
  int e   = idx & 4095;
  int m   = e >> 5, col = e & 31;
  int o   = bm * 128 + m;
  int k   = kt * 32 + (col ^ swz32(m));
  g_wbf[idx] = f2bf(wgt[o * CIN_ + k]);
}

__global__ __launch_bounds__(256, 4)
void shiftconv_gemm(const float* __restrict__ x,
                    const float* __restrict__ gamma,
                    const float* __restrict__ beta,
                    const float* __restrict__ rmean,
                    const float* __restrict__ rvar,
                    float* __restrict__ out)
{
  // Double-buffered: A [128 m][32 k] bf16, B [64 n][32 k] bf16, both k-contig,
  // cols XOR-swizzled by ((row^(row>>3))&3)<<3 -> b128 reads/writes <=2-way banked.
  __shared__ unsigned short Alds[2][128 * 32];   // 2 x 8 KB
  __shared__ unsigned short Blds[2][64 * 32];    // 2 x 4 KB
  __shared__ float bnp[256];                     // interleaved (inv, add)

  const int t = threadIdx.x;
  // XCD-bijective swizzle (nwg = 3136 = 8*392): bm-pairs (same bn -> same x
  // slice) land adjacent on the same XCD -> second read is an L2/L3 hit.
  const int orig = blockIdx.x;
  const int wgid = (orig & 7) * 392 + (orig >> 3);
  const int bm   = wgid & 1;     // 2 m-tiles of 128
  const int bn   = wgid >> 1;    // 1568 n-tiles of 64

  const int lane = t & 63;
  const int wv   = t >> 6;
  const int wm   = wv >> 1;      // wave m-half (64 rows)
  const int wn   = wv & 1;       // wave n-half (32 cols)
  const int quad = lane >> 4;
  const int l15  = lane & 15;

  if (t < 128) {
    int o = bm * 128 + t;
    float inv = gamma[o] * rsqrtf(rvar[o] + 1e-5f);
    bnp[2 * t]     = inv;
    bnp[2 * t + 1] = beta[o] - rmean[o] * inv;
  }

  // ---- B staging decode: thread owns 1 n-row x 8 k (k-contiguous) ----
  // Lane-consecutive n -> each channel's load is a coalesced 256B wave read;
  // the 8 bf16 results are k-contiguous -> ONE ds_write_b128 per thread.
  const int nl    = t & 63;            // n within tile (= lane)
  const int kk    = (t >> 6) * 8;      // k-octet within tile (wave-uniform)
  const int nglob = bn * 64 + nl;
  const int bidx  = nglob / HW_;       // HW_=3136 divisible by 64: tile within 1 image
  const int rem   = nglob - bidx * HW_;
  const int hh    = rem / W_;
  const int ww    = rem - hh * W_;
  const size_t xb = (size_t)bidx * CIN_ * HW_;
  unsigned short* bdst0 = &Blds[0][nl * 32 + (kk ^ swz32(nl))];
  unsigned short* bdst1 = &Blds[1][nl * 32 + (kk ^ swz32(nl))];

  // ---- A staging source: pre-swizzled bf16 weights ----
  const unsigned short* wsrc = g_wbf + bm * (8 * 4096) + t * 8;

  f32x4 acc[4][2];
  #pragma unroll
  for (int i = 0; i < 4; ++i)
    #pragma unroll
    for (int j = 0; j < 2; ++j)
      acc[i][j] = (f32x4){0.f, 0.f, 0.f, 0.f};

  float fv[8];   // raw x values for next tile (statically indexed via unroll)

  // loadB: gather 8 channels (shifted, zero-padded) for this thread's n-row.
  auto loadB = [&](int ktile) {
    #pragma unroll
    for (int j = 0; j < 8; ++j) {
      int c = ktile * 32 + kk + j;           // wave-uniform channel
      int dx, dy; shift_decode(c, dx, dy);
      int h2 = hh - dy, w2 = ww - dx;        // per-lane bounds
      float v = 0.f;
      if ((unsigned)h2 < (unsigned)H_ && (unsigned)w2 < (unsigned)W_)
        v = x[xb + (size_t)c * HW_ + h2 * W_ + w2];
      fv[j] = v;
    }
  };
  auto writeB = [&](unsigned short* dst) {
    union { short8 v; unsigned short s[8]; } pk;
    #pragma unroll
    for (int j = 0; j < 8; ++j) pk.s[j] = f2bf(fv[j]);
    *(short8*)dst = pk.v;
  };

  // ---- prologue: stage tile 0 ----
  {
    const unsigned short* g = wsrc;
    gload_lds16(g,        &Alds[0][wv * 512]);
    gload_lds16(g + 2048, &Alds[0][wv * 512 + 2048]);
  }
  loadB(0);
  writeB(bdst0);
  __syncthreads();

  const int kb = quad * 8;
  int buf = 0;

  // ---- main loop: one barrier per K-tile; next tile's loads in flight over MFMA ----
  for (int kt = 0; kt < 8; ++kt) {
    if (kt < 7) {
      const unsigned short* g = wsrc + (kt + 1) * 4096;
      gload_lds16(g,        &Alds[buf ^ 1][wv * 512]);
      gload_lds16(g + 2048, &Alds[buf ^ 1][wv * 512 + 2048]);
      loadB(kt + 1);
    }

    short8 af[4], bfr[2];
    #pragma unroll
    for (int f = 0; f < 4; ++f) {
      int ml = wm * 64 + f * 16 + l15;
      af[f] = *(const short8*)(&Alds[buf][ml * 32 + (kb ^ swz32(ml))]);
    }
    #pragma unroll
    for (int g2 = 0; g2 < 2; ++g2) {
      int nl2 = wn * 32 + g2 * 16 + l15;
      bfr[g2] = *(const short8*)(&Blds[buf][nl2 * 32 + (kb ^ swz32(nl2))]);
    }
    #pragma unroll
    for (int mf = 0; mf < 4; ++mf)
      #pragma unroll
      for (int nf = 0; nf < 2; ++nf)
        acc[mf][nf] = __builtin_amdgcn_mfma_f32_16x16x32_bf16(
            af[mf], bfr[nf], acc[mf][nf], 0, 0, 0);

    if (kt < 7)
      writeB((buf ^ 1) ? bdst1 : bdst0);

    __syncthreads();
    buf ^= 1;
  }

  // ---- epilogue: BN + ReLU + fp32 store ----
  size_t nbase[2];
  #pragma unroll
  for (int nf = 0; nf < 2; ++nf) {
    int ng  = bn * 64 + wn * 32 + nf * 16 + l15;
    int b2  = ng / HW_;
    int hw2 = ng - b2 * HW_;
    nbase[nf] = (size_t)b2 * COUT_ * HW_ + hw2;
  }
  #pragma unroll
  for (int mf = 0; mf < 4; ++mf) {
    int mloc = wm * 64 + mf * 16 + quad * 4;   // local o for reg r=0
    float inv[4], add[4];
    #pragma unroll
    for (int r = 0; r < 4; ++r) {
      inv[r] = bnp[2 * (mloc + r)];
      add[r] = bnp[2 * (mloc + r) + 1];
    }
    size_t obase = (size_t)(bm * 128 + mloc) * HW_;
    #pragma unroll
    for (int nf = 0; nf < 2; ++nf) {
      #pragma unroll
      for (int r = 0; r < 4; ++r) {
        float v = fmaf(acc[mf][nf][r], inv[r], add[r]);
        out[nbase[nf] + obase + (size_t)r * HW_] = fmaxf(v, 0.0f);
      }
    }
  }
}

extern "C" void kernel_launch(void* const* d_in, const int* in_sizes, int n_in,
                              void* d_out, int out_size, void* d_ws, size_t ws_size,
                              hipStream_t stream) {
  const float* x     = (const float*)d_in[0];
  const float* wgt   = (const float*)d_in[1];
  const float* gamma = (const float*)d_in[2];
  const float* beta  = (const float*)d_in[3];
  const float* rmean = (const float*)d_in[4];
  const float* rvar  = (const float*)d_in[5];
  float* out = (float*)d_out;

  prep_weights<<<dim3(256), dim3(256), 0, stream>>>(wgt);
  shiftconv_gemm<<<dim3(3136), dim3(256), 0, stream>>>(x, gamma, beta, rmean, rvar, out);
}